// Round 3
// baseline (53.304 us; speedup 1.0000x reference)
//
#include <hip/hip_runtime.h>

#define Bz 32
#define Lz 1024
#define Hz 768
#define Sz 16

typedef float f32x4 __attribute__((ext_vector_type(4)));

// ---------------- kernel 1: fused mask rows + per-position dot ----------------
// one block per (b, q) row; 256 threads.
// Row structure (derived from reference semantics):
//   q >= v           : all zeros
//   q <  hist        : ones on [0, v)
//   hist <= q < v    : ones on [0, hist) U [s0, s1)  where [s0,s1) is q's segment
// (segment bounds all lie in [hist, v], so the two intervals never overlap)
__global__ __launch_bounds__(256) void fused_mask_dot(
    const float* __restrict__ tokens, const int* __restrict__ amask,
    const int* __restrict__ bos, const float* __restrict__ fc_w,
    float* __restrict__ maskOut, float* __restrict__ t) {
  int b = blockIdx.x >> 10;  // grid = Bz*Lz
  int q = blockIdx.x & (Lz - 1);
  int tid = threadIdx.x;

  __shared__ int sbos[Sz];
  __shared__ int firsts[257];
  __shared__ int vsh;
  __shared__ float wsum[4];

  if (tid < Sz) sbos[tid] = bos[b * Sz + tid];
  // valid-length detect: amask row is monotone 1...10...0, valid in [L/2, L]
  const int4* am4 = (const int4*)(amask + b * Lz);
  int4 a4 = am4[tid];
  firsts[tid] = a4.x;
  if (tid == 0) firsts[256] = 0;  // sentinel for v == L
  __syncthreads();
  int nxt = firsts[tid + 1];
  int p0 = tid * 4;
  if (a4.x && !a4.y) vsh = p0 + 1;
  else if (a4.y && !a4.z) vsh = p0 + 2;
  else if (a4.z && !a4.w) vsh = p0 + 3;
  else if (a4.w && !nxt) vsh = p0 + 4;
  __syncthreads();
  int v = vsh;
  int h = sbos[0];

  int A, s0, s1;
  if (q >= v) { A = 0; s0 = 0; s1 = 0; }
  else if (q < h) { A = v; s0 = 0; s1 = 0; }
  else {
    int idx = -1;
#pragma unroll
    for (int s = 0; s < Sz; ++s) idx += (q >= sbos[s]) ? 1 : 0;
    A = h;
    s0 = sbos[idx];
    s1 = (idx < Sz - 1) ? sbos[idx + 1] : v;
  }

  f32x4 val;
  val.x = (p0 + 0 < A || (p0 + 0 >= s0 && p0 + 0 < s1)) ? 1.f : 0.f;
  val.y = (p0 + 1 < A || (p0 + 1 >= s0 && p0 + 1 < s1)) ? 1.f : 0.f;
  val.z = (p0 + 2 < A || (p0 + 2 >= s0 && p0 + 2 < s1)) ? 1.f : 0.f;
  val.w = (p0 + 3 < A || (p0 + 3 >= s0 && p0 + 3 < s1)) ? 1.f : 0.f;
  f32x4* row = (f32x4*)(maskOut + ((size_t)(b * Lz + q)) * Lz);
  __builtin_nontemporal_store(val, row + tid);

  // per-position dot for rows that feed the segment means (q in [hist, v))
  if (q >= h && q < v) {
    float partial = 0.f;
    if (tid < Hz / 4) {  // 192 threads x float4 = 768 floats
      const f32x4* tp = (const f32x4*)(tokens + ((size_t)b * Lz + q) * Hz);
      const f32x4* wp = (const f32x4*)fc_w;
      f32x4 x = __builtin_nontemporal_load(tp + tid);
      f32x4 w = wp[tid];
      partial = x.x * w.x + x.y * w.y + x.z * w.z + x.w * w.w;
    }
#pragma unroll
    for (int off = 32; off > 0; off >>= 1) partial += __shfl_down(partial, off);
    if ((tid & 63) == 0) wsum[tid >> 6] = partial;
    __syncthreads();
    if (tid == 0) t[b * Lz + q] = wsum[0] + wsum[1] + wsum[2];
  }
}

// ---------------- kernel 2: segment means -> logits ----------------
__global__ __launch_bounds__(64) void logits_kernel(
    const float* __restrict__ t, const int* __restrict__ bos,
    const int* __restrict__ amask, const float* __restrict__ fc_b,
    float* __restrict__ logits) {
  int b = blockIdx.x >> 4;  // grid = Bz*Sz
  int s = blockIdx.x & (Sz - 1);
  int lane = threadIdx.x;
  // valid = popcount of the (L2-resident) amask row
  const int4* am4 = (const int4*)(amask + b * Lz);
  int vsum = 0;
#pragma unroll
  for (int c = 0; c < 4; ++c) {
    int4 a = am4[lane + c * 64];
    vsum += a.x + a.y + a.z + a.w;
  }
#pragma unroll
  for (int off = 32; off > 0; off >>= 1) vsum += __shfl_down(vsum, off);
  vsum = __shfl(vsum, 0);
  int beg = bos[b * Sz + s];
  int end = (s < Sz - 1) ? bos[b * Sz + s + 1] : vsum;
  float sum = 0.f;
  for (int p = beg + lane; p < end; p += 64) sum += t[b * Lz + p];
#pragma unroll
  for (int off = 32; off > 0; off >>= 1) sum += __shfl_down(sum, off);
  if (lane == 0) logits[b * Sz + s] = sum / (float)(end - beg) + fc_b[0];
}

extern "C" void kernel_launch(void* const* d_in, const int* in_sizes, int n_in,
                              void* d_out, int out_size, void* d_ws, size_t ws_size,
                              hipStream_t stream) {
  const float* tokens = (const float*)d_in[0];
  const int* amask = (const int*)d_in[1];
  const int* bos = (const int*)d_in[2];
  const float* fc_w = (const float*)d_in[3];
  const float* fc_b = (const float*)d_in[4];

  float* out = (float*)d_out;
  float* logits = out;             // Bz*Sz floats
  float* maskOut = out + Bz * Sz;  // Bz*Lz*Lz floats (0/1)

  float* t = (float*)d_ws;  // Bz*Lz floats of per-position dots

  fused_mask_dot<<<Bz * Lz, 256, 0, stream>>>(tokens, amask, bos, fc_w, maskOut, t);
  logits_kernel<<<Bz * Sz, 64, 0, stream>>>(t, bos, amask, fc_b, logits);
}

// Round 4
// 39.521 us; speedup vs baseline: 1.3487x; 1.3487x over previous
//
#include <hip/hip_runtime.h>

#define Bz 32
#define Lz 1024
#define Hz 768
#define Sz 16

typedef float f32x4 __attribute__((ext_vector_type(4)));

// ---------------- kernel 1: per-batch setup (tiny) ----------------
// valid[b] = sum(attention_mask[b]) (mask is monotone 1..10..0), hist[b] = bos[b][0]
__global__ __launch_bounds__(256) void setup_kernel(
    const int* __restrict__ amask, const int* __restrict__ bos,
    int* __restrict__ validArr, int* __restrict__ histArr) {
  int b = blockIdx.x;
  int tid = threadIdx.x;
  __shared__ int red[256];
  const int4* am4 = (const int4*)(amask + b * Lz);
  int4 a = am4[tid];
  red[tid] = a.x + a.y + a.z + a.w;
  __syncthreads();
  for (int off = 128; off > 0; off >>= 1) {
    if (tid < off) red[tid] += red[tid + off];
    __syncthreads();
  }
  if (tid == 0) { validArr[b] = red[0]; histArr[b] = bos[b * Sz]; }
}

// ---------------- kernel 2: fused mask rows + per-position dot ----------------
// grid = Bz * (Lz/16) blocks, 256 threads; each wave owns 4 consecutive rows.
// Row structure (derived from reference semantics):
//   q >= v        : all zeros
//   q <  hist     : ones on [0, v)
//   hist <= q < v : ones on [0, hist) U [s0, s1)  where [s0,s1) is q's segment
__global__ __launch_bounds__(256) void fused_mask_dot(
    const float* __restrict__ tokens, const int* __restrict__ bos,
    const int* __restrict__ validArr, const int* __restrict__ histArr,
    const float* __restrict__ fc_w, float* __restrict__ maskOut,
    float* __restrict__ t) {
  int b = blockIdx.x >> 6;              // grid = Bz * 64
  int qbase = (blockIdx.x & 63) * 16;   // 16 rows per block
  int wave = threadIdx.x >> 6;
  int lane = threadIdx.x & 63;

  int v = validArr[b];
  int h = histArr[b];
  const int* bosRow = bos + b * Sz;

  const f32x4* wp = (const f32x4*)fc_w;

#pragma unroll
  for (int it = 0; it < 4; ++it) {
    int q = qbase + wave * 4 + it;

    int A, s0, s1;
    if (q >= v) { A = 0; s0 = 0; s1 = 0; }
    else if (q < h) { A = v; s0 = 0; s1 = 0; }
    else {
      int idx = -1;
#pragma unroll
      for (int s = 0; s < Sz; ++s) idx += (q >= bosRow[s]) ? 1 : 0;
      A = h;
      s0 = bosRow[idx];
      s1 = (idx < Sz - 1) ? bosRow[idx + 1] : v;
    }

    // write the 4 KB row: 4 stores of 16 B per lane, contiguous 1 KB per instr
    f32x4* row = (f32x4*)(maskOut + ((size_t)(b * Lz + q)) * Lz);
#pragma unroll
    for (int j = 0; j < 4; ++j) {
      int p0 = (lane + j * 64) * 4;
      f32x4 val;
      val.x = (p0 + 0 < A || (p0 + 0 >= s0 && p0 + 0 < s1)) ? 1.f : 0.f;
      val.y = (p0 + 1 < A || (p0 + 1 >= s0 && p0 + 1 < s1)) ? 1.f : 0.f;
      val.z = (p0 + 2 < A || (p0 + 2 >= s0 && p0 + 2 < s1)) ? 1.f : 0.f;
      val.w = (p0 + 3 < A || (p0 + 3 >= s0 && p0 + 3 < s1)) ? 1.f : 0.f;
      row[lane + j * 64] = val;
    }

    // per-position dot for rows that feed the segment means (q in [hist, v))
    if (q >= h && q < v) {
      const f32x4* tp = (const f32x4*)(tokens + ((size_t)b * Lz + q) * Hz);
      float sum = 0.f;
#pragma unroll
      for (int c = 0; c < 3; ++c) {  // 192 float4 = 64 lanes * 3
        f32x4 x = tp[lane + c * 64];
        f32x4 w = wp[lane + c * 64];
        sum += x.x * w.x + x.y * w.y + x.z * w.z + x.w * w.w;
      }
#pragma unroll
      for (int off = 32; off > 0; off >>= 1) sum += __shfl_down(sum, off);
      if (lane == 0) t[b * Lz + q] = sum;
    }
  }
}

// ---------------- kernel 3: segment means -> logits ----------------
__global__ __launch_bounds__(64) void logits_kernel(
    const float* __restrict__ t, const int* __restrict__ bos,
    const int* __restrict__ validArr, const float* __restrict__ fc_b,
    float* __restrict__ logits) {
  int b = blockIdx.x >> 4;  // grid = Bz*Sz
  int s = blockIdx.x & (Sz - 1);
  int lane = threadIdx.x;
  int beg = bos[b * Sz + s];
  int end = (s < Sz - 1) ? bos[b * Sz + s + 1] : validArr[b];
  float sum = 0.f;
  for (int p = beg + lane; p < end; p += 64) sum += t[b * Lz + p];
#pragma unroll
  for (int off = 32; off > 0; off >>= 1) sum += __shfl_down(sum, off);
  if (lane == 0) logits[b * Sz + s] = sum / (float)(end - beg) + fc_b[0];
}

extern "C" void kernel_launch(void* const* d_in, const int* in_sizes, int n_in,
                              void* d_out, int out_size, void* d_ws, size_t ws_size,
                              hipStream_t stream) {
  const float* tokens = (const float*)d_in[0];
  const int* amask = (const int*)d_in[1];
  const int* bos = (const int*)d_in[2];
  const float* fc_w = (const float*)d_in[3];
  const float* fc_b = (const float*)d_in[4];

  float* out = (float*)d_out;
  float* logits = out;             // Bz*Sz floats
  float* maskOut = out + Bz * Sz;  // Bz*Lz*Lz floats (0/1)

  char* ws = (char*)d_ws;
  float* t = (float*)ws;                       // Bz*Lz floats
  int* validArr = (int*)(ws + Bz * Lz * 4);    // Bz ints
  int* histArr = validArr + Bz;                // Bz ints

  setup_kernel<<<Bz, 256, 0, stream>>>(amask, bos, validArr, histArr);
  fused_mask_dot<<<Bz * (Lz / 16), 256, 0, stream>>>(tokens, bos, validArr, histArr,
                                                     fc_w, maskOut, t);
  logits_kernel<<<Bz * Sz, 64, 0, stream>>>(t, bos, validArr, fc_b, logits);
}

// Round 5
// 38.552 us; speedup vs baseline: 1.3826x; 1.0251x over previous
//
#include <hip/hip_runtime.h>

#define Bz 32
#define Lz 1024
#define Hz 768
#define Sz 16

typedef float f32x4 __attribute__((ext_vector_type(4)));

// ---------------- kernel 1: per-batch setup (tiny) ----------------
__global__ __launch_bounds__(256) void setup_kernel(
    const int* __restrict__ amask, const int* __restrict__ bos,
    int* __restrict__ validArr, int* __restrict__ histArr) {
  int b = blockIdx.x;
  int tid = threadIdx.x;
  __shared__ int red[256];
  const int4* am4 = (const int4*)(amask + b * Lz);
  int4 a = am4[tid];
  red[tid] = a.x + a.y + a.z + a.w;
  __syncthreads();
  for (int off = 128; off > 0; off >>= 1) {
    if (tid < off) red[tid] += red[tid + off];
    __syncthreads();
  }
  if (tid == 0) { validArr[b] = red[0]; histArr[b] = bos[b * Sz]; }
}

// ---------------- kernel 2: fused mask rows + per-position dot ----------------
// grid = Bz * 64 blocks, 256 threads (4 waves); each wave owns 4 rows,
// strided by 256 across the batch for CU/wave load balance:
//   q = local + (it*4 + wave) * 64,  local = blockIdx % 64
// Row structure (derived from reference semantics):
//   q >= v        : all zeros
//   q <  hist     : ones on [0, v)
//   hist <= q < v : ones on [0, hist) U [s0, s1)  where [s0,s1) is q's segment
__global__ __launch_bounds__(256) void fused_mask_dot(
    const float* __restrict__ tokens, const int* __restrict__ bos,
    const int* __restrict__ validArr, const int* __restrict__ histArr,
    const float* __restrict__ fc_w, float* __restrict__ maskOut,
    float* __restrict__ t) {
  int b = blockIdx.x >> 6;
  int local = blockIdx.x & 63;
  int wave = threadIdx.x >> 6;
  int lane = threadIdx.x & 63;

  int v = validArr[b];
  int h = histArr[b];
  const int* bosRow = bos + b * Sz;

  // uniform weight fragments, hoisted (L1/L2-resident)
  const f32x4* wp = (const f32x4*)fc_w;
  f32x4 w0 = wp[lane];
  f32x4 w1 = wp[lane + 64];
  f32x4 w2 = wp[lane + 128];

#pragma unroll
  for (int it = 0; it < 4; ++it) {
    int q = local + ((it << 2) + wave) * 64;
    bool doDot = (q >= h && q < v);

    // issue token loads early so they overlap the mask store stream
    const f32x4* tp = (const f32x4*)(tokens + ((size_t)(b * Lz + q)) * Hz);
    f32x4 x0, x1, x2;
    if (doDot) {
      x0 = tp[lane];
      x1 = tp[lane + 64];
      x2 = tp[lane + 128];
    }

    int A, s0, s1;
    if (q >= v) { A = 0; s0 = 0; s1 = 0; }
    else if (q < h) { A = v; s0 = 0; s1 = 0; }
    else {
      int idx = -1;
#pragma unroll
      for (int s = 0; s < Sz; ++s) idx += (q >= bosRow[s]) ? 1 : 0;
      A = h;
      s0 = bosRow[idx];
      s1 = (idx < Sz - 1) ? bosRow[idx + 1] : v;
    }
    unsigned span = (unsigned)(s1 - s0);

    f32x4* row = (f32x4*)(maskOut + ((size_t)(b * Lz + q)) * Lz);
#pragma unroll
    for (int j = 0; j < 4; ++j) {
      int p0 = (lane + j * 64) * 4;
      f32x4 val;
      val.x = (p0 + 0 < A || (unsigned)(p0 + 0 - s0) < span) ? 1.f : 0.f;
      val.y = (p0 + 1 < A || (unsigned)(p0 + 1 - s0) < span) ? 1.f : 0.f;
      val.z = (p0 + 2 < A || (unsigned)(p0 + 2 - s0) < span) ? 1.f : 0.f;
      val.w = (p0 + 3 < A || (unsigned)(p0 + 3 - s0) < span) ? 1.f : 0.f;
      row[lane + j * 64] = val;
    }

    if (doDot) {
      float sum = x0.x * w0.x + x0.y * w0.y + x0.z * w0.z + x0.w * w0.w;
      sum += x1.x * w1.x + x1.y * w1.y + x1.z * w1.z + x1.w * w1.w;
      sum += x2.x * w2.x + x2.y * w2.y + x2.z * w2.z + x2.w * w2.w;
#pragma unroll
      for (int off = 32; off > 0; off >>= 1) sum += __shfl_down(sum, off);
      if (lane == 0) t[b * Lz + q] = sum;
    }
  }
}

// ---------------- kernel 3: segment means -> logits ----------------
__global__ __launch_bounds__(64) void logits_kernel(
    const float* __restrict__ t, const int* __restrict__ bos,
    const int* __restrict__ validArr, const float* __restrict__ fc_b,
    float* __restrict__ logits) {
  int b = blockIdx.x >> 4;  // grid = Bz*Sz
  int s = blockIdx.x & (Sz - 1);
  int lane = threadIdx.x;
  int beg = bos[b * Sz + s];
  int end = (s < Sz - 1) ? bos[b * Sz + s + 1] : validArr[b];
  float sum = 0.f;
  for (int p = beg + lane; p < end; p += 64) sum += t[b * Lz + p];
#pragma unroll
  for (int off = 32; off > 0; off >>= 1) sum += __shfl_down(sum, off);
  if (lane == 0) logits[b * Sz + s] = sum / (float)(end - beg) + fc_b[0];
}

extern "C" void kernel_launch(void* const* d_in, const int* in_sizes, int n_in,
                              void* d_out, int out_size, void* d_ws, size_t ws_size,
                              hipStream_t stream) {
  const float* tokens = (const float*)d_in[0];
  const int* amask = (const int*)d_in[1];
  const int* bos = (const int*)d_in[2];
  const float* fc_w = (const float*)d_in[3];
  const float* fc_b = (const float*)d_in[4];

  float* out = (float*)d_out;
  float* logits = out;             // Bz*Sz floats
  float* maskOut = out + Bz * Sz;  // Bz*Lz*Lz floats (0/1)

  char* ws = (char*)d_ws;
  float* t = (float*)ws;                       // Bz*Lz floats
  int* validArr = (int*)(ws + Bz * Lz * 4);    // Bz ints
  int* histArr = validArr + Bz;                // Bz ints

  setup_kernel<<<Bz, 256, 0, stream>>>(amask, bos, validArr, histArr);
  fused_mask_dot<<<Bz * 64, 256, 0, stream>>>(tokens, bos, validArr, histArr,
                                              fc_w, maskOut, t);
  logits_kernel<<<Bz * Sz, 64, 0, stream>>>(t, bos, validArr, fc_b, logits);
}

// Round 6
// 35.371 us; speedup vs baseline: 1.5070x; 1.0899x over previous
//
#include <hip/hip_runtime.h>

#define Bz 32
#define Lz 1024
#define Hz 768
#define Sz 16

typedef float f32x4 __attribute__((ext_vector_type(4)));

// valid length of a monotone 1..10..0 amask row, computed wave-locally:
// 4 int4 loads per lane (row is 256 int4s), 15 adds, butterfly reduce.
__device__ __forceinline__ int wave_valid(const int* __restrict__ amaskRow, int lane) {
  const int4* am4 = (const int4*)amaskRow;
  int s = 0;
#pragma unroll
  for (int j = 0; j < 4; ++j) {
    int4 a = am4[lane + j * 64];
    s += a.x + a.y + a.z + a.w;
  }
#pragma unroll
  for (int off = 32; off > 0; off >>= 1) s += __shfl_xor(s, off);
  return s;  // in all lanes
}

// ---------------- kernel 1: fused mask rows + per-position dot ----------------
// grid = Bz * 64 blocks, 256 threads (4 waves); each wave owns 4 rows,
// strided by 64 for CU/wave load balance: q = local + (it*4 + wave) * 64.
// Row structure (derived from reference semantics):
//   q >= v        : all zeros
//   q <  hist     : ones on [0, v)
//   hist <= q < v : ones on [0, hist) U [s0, s1)  where [s0,s1) is q's segment
__global__ __launch_bounds__(256) void fused_mask_dot(
    const float* __restrict__ tokens, const int* __restrict__ amask,
    const int* __restrict__ bos, const float* __restrict__ fc_w,
    float* __restrict__ maskOut, float* __restrict__ t) {
  int b = blockIdx.x >> 6;
  int local = blockIdx.x & 63;
  int wave = threadIdx.x >> 6;
  int lane = threadIdx.x & 63;

  int v = wave_valid(amask + b * Lz, lane);
  const int* bosRow = bos + b * Sz;
  int h = bosRow[0];

  // uniform weight fragments, hoisted (L1/L2-resident)
  const f32x4* wp = (const f32x4*)fc_w;
  f32x4 w0 = wp[lane];
  f32x4 w1 = wp[lane + 64];
  f32x4 w2 = wp[lane + 128];

#pragma unroll
  for (int it = 0; it < 4; ++it) {
    int q = local + ((it << 2) + wave) * 64;
    bool doDot = (q >= h && q < v);

    // issue token loads early so they overlap the mask store stream
    const f32x4* tp = (const f32x4*)(tokens + ((size_t)(b * Lz + q)) * Hz);
    f32x4 x0, x1, x2;
    if (doDot) {
      x0 = tp[lane];
      x1 = tp[lane + 64];
      x2 = tp[lane + 128];
    }

    int A, s0, s1;
    if (q >= v) { A = 0; s0 = 0; s1 = 0; }
    else if (q < h) { A = v; s0 = 0; s1 = 0; }
    else {
      int idx = -1;
#pragma unroll
      for (int s = 0; s < Sz; ++s) idx += (q >= bosRow[s]) ? 1 : 0;
      A = h;
      s0 = bosRow[idx];
      s1 = (idx < Sz - 1) ? bosRow[idx + 1] : v;
    }
    unsigned span = (unsigned)(s1 - s0);

    f32x4* row = (f32x4*)(maskOut + ((size_t)(b * Lz + q)) * Lz);
#pragma unroll
    for (int j = 0; j < 4; ++j) {
      int p0 = (lane + j * 64) * 4;
      f32x4 val;
      val.x = (p0 + 0 < A || (unsigned)(p0 + 0 - s0) < span) ? 1.f : 0.f;
      val.y = (p0 + 1 < A || (unsigned)(p0 + 1 - s0) < span) ? 1.f : 0.f;
      val.z = (p0 + 2 < A || (unsigned)(p0 + 2 - s0) < span) ? 1.f : 0.f;
      val.w = (p0 + 3 < A || (unsigned)(p0 + 3 - s0) < span) ? 1.f : 0.f;
      row[lane + j * 64] = val;
    }

    if (doDot) {
      float sum = x0.x * w0.x + x0.y * w0.y + x0.z * w0.z + x0.w * w0.w;
      sum += x1.x * w1.x + x1.y * w1.y + x1.z * w1.z + x1.w * w1.w;
      sum += x2.x * w2.x + x2.y * w2.y + x2.z * w2.z + x2.w * w2.w;
#pragma unroll
      for (int off = 32; off > 0; off >>= 1) sum += __shfl_down(sum, off);
      if (lane == 0) t[b * Lz + q] = sum;
    }
  }
}

// ---------------- kernel 2: segment means -> logits ----------------
// one block per batch, 16 waves = one per segment; each wave recomputes v
// from the (L2-hot) amask row, then sums its segment's t values.
__global__ __launch_bounds__(1024) void logits_kernel(
    const float* __restrict__ t, const int* __restrict__ bos,
    const int* __restrict__ amask, const float* __restrict__ fc_b,
    float* __restrict__ logits) {
  int b = blockIdx.x;
  int s = threadIdx.x >> 6;
  int lane = threadIdx.x & 63;

  int v = wave_valid(amask + b * Lz, lane);
  int beg = bos[b * Sz + s];
  int end = (s < Sz - 1) ? bos[b * Sz + s + 1] : v;

  float sum = 0.f;
  for (int p = beg + lane; p < end; p += 64) sum += t[b * Lz + p];
#pragma unroll
  for (int off = 32; off > 0; off >>= 1) sum += __shfl_down(sum, off);
  if (lane == 0) logits[b * Sz + s] = sum / (float)(end - beg) + fc_b[0];
}

extern "C" void kernel_launch(void* const* d_in, const int* in_sizes, int n_in,
                              void* d_out, int out_size, void* d_ws, size_t ws_size,
                              hipStream_t stream) {
  const float* tokens = (const float*)d_in[0];
  const int* amask = (const int*)d_in[1];
  const int* bos = (const int*)d_in[2];
  const float* fc_w = (const float*)d_in[3];
  const float* fc_b = (const float*)d_in[4];

  float* out = (float*)d_out;
  float* logits = out;             // Bz*Sz floats
  float* maskOut = out + Bz * Sz;  // Bz*Lz*Lz floats (0/1)

  float* t = (float*)d_ws;  // Bz*Lz floats of per-position dots

  fused_mask_dot<<<Bz * 64, 256, 0, stream>>>(tokens, amask, bos, fc_w, maskOut, t);
  logits_kernel<<<Bz, 1024, 0, stream>>>(t, bos, amask, fc_b, logits);
}